// Round 4
// baseline (271.908 us; speedup 1.0000x reference)
//
#include <hip/hip_runtime.h>
#include <hip/hip_bf16.h>
#include <math.h>

// Problem constants (match reference)
#define Bg 16
#define Nn 2048
#define Ee (1<<20)
#define NT (Bg*Nn)
#define INC 256
#define DIMd 128
#define OUTC 6
#define ENCH 100
#define NATOMS 20

typedef __attribute__((ext_vector_type(8))) short bf16x8;
typedef __attribute__((ext_vector_type(4))) float f32x4;

__device__ __forceinline__ float gelu_f(float x){
    return 0.5f*x*(1.0f+erff(x*0.70710678118654752440f));
}
__device__ __forceinline__ unsigned short f2b(float f){
    __hip_bfloat16 h = __float2bfloat16(f);
    return *(unsigned short*)&h;
}
__device__ __forceinline__ float b2f(unsigned short u){
    unsigned v = ((unsigned)u)<<16;
    return __uint_as_float(v);
}
// split fp32 into bf16 hi + bf16 lo (v ~= hi + lo, dropped residual ~2^-18 rel)
__device__ __forceinline__ void splitf(float v, unsigned short& hi, unsigned short& lo){
    unsigned short h = f2b(v);
    hi = h; lo = f2b(v - b2f(h));
}

// ---- Kernel 1: prep0 = BN stats (blocks 0..255) + weight split (256..319) --
__global__ __launch_bounds__(256) void prep0_k(const float* __restrict__ x,
    float* __restrict__ stats, const float* __restrict__ W1,
    const float* __restrict__ W2, const float* __restrict__ Wm,
    const float* __restrict__ A1, short* __restrict__ w1th, short* __restrict__ w1tl,
    short* __restrict__ w2th, short* __restrict__ w2tl,
    short* __restrict__ wmth, short* __restrict__ wmtl,
    short* __restrict__ a1th, short* __restrict__ a1tl)
{
    int bx = blockIdx.x, tid = threadIdx.x;
    if(bx < 256){
        int c = tid;
        int r0 = bx * 128;
        const float* p = x + (size_t)r0*INC + c;
        float s = 0.f, s2 = 0.f;
        #pragma unroll 8
        for(int r=0;r<128;r++){ float v = p[(size_t)r*INC]; s += v; s2 += v*v; }
        atomicAdd(&stats[c], s);
        atomicAdd(&stats[INC+c], s2);
    } else {
        int gid = (bx-256)*256 + tid;             // 64 blocks -> 16384 threads
        unsigned short hi, lo;
        for(int l=gid;l<65536;l+=16384){ int n=l>>8,k=l&255;
            splitf(W1[(size_t)k*256+n],hi,lo); w1th[l]=(short)hi; w1tl[l]=(short)lo; }
        for(int l=gid;l<32768;l+=16384){ int n=l>>8,k=l&255;
            splitf(W2[(size_t)k*128+n],hi,lo); w2th[l]=(short)hi; w2tl[l]=(short)lo; }
        for(int l=gid;l<16384;l+=16384){ int n=l>>7,k=l&127;
            splitf(Wm[(size_t)k*128+n],hi,lo); wmth[l]=(short)hi; wmtl[l]=(short)lo; }
        for(int l=gid;l<16384;l+=16384){ int n=l>>7,k=l&127;
            float v=(n<ENCH)? A1[(size_t)k*ENCH+n] : 0.f;
            splitf(v,hi,lo); a1th[l]=(short)hi; a1tl[l]=(short)lo; }
    }
}

// ---- Kernel 2: h1 = gelu(BN(x)@W1+b1), 64x256 tile, 3-term split MFMA ------
// + edge-scatter (2048 edges/block) AFTER the GEMM: atomics drain at kernel
//   end only (no barrier between), hidden under other blocks' MFMA work.
// grid 512. 4 waves: 2m x 2n, wave = 32m x 128n (8 tn tiles).
__global__ __launch_bounds__(256) void gemm1_adj_k(const float* __restrict__ x,
    const float* __restrict__ stats, const float* __restrict__ gamma,
    const float* __restrict__ beta, const short* __restrict__ w1th,
    const short* __restrict__ w1tl, const float* __restrict__ b1,
    unsigned short* __restrict__ h1h, unsigned short* __restrict__ h1l,
    const int* __restrict__ ei, unsigned* __restrict__ mask)
{
    __shared__ float sc[256], sh[256];
    __shared__ short sAh[64*40], sAl[64*40];     // pad 40: 16B-aligned frags
    __shared__ short sBh[256*40], sBl[256*40];
    int tid = threadIdx.x;
    {
        float mu  = stats[tid]*(1.0f/NT);
        float var = stats[256+tid]*(1.0f/NT) - mu*mu;
        float s = gamma[tid]/sqrtf(var + 1e-5f);
        sc[tid] = s; sh[tid] = beta[tid] - mu*s;
    }
    int row0 = blockIdx.x*64;
    int lane = tid&63, w = tid>>6;
    int ln = lane&15, quad = lane>>4;
    int m0w = (w&1)*32, n0b = (w>>1)*128;
    f32x4 acc[2][8];
    #pragma unroll
    for(int i=0;i<2;i++)
        #pragma unroll
        for(int j=0;j<8;j++) acc[i][j] = (f32x4){0.f,0.f,0.f,0.f};
    __syncthreads();
    for(int k0=0;k0<256;k0+=32){
        #pragma unroll
        for(int i=0;i<2;i++){                       // A: BN(x) 64x32 split
            int id = tid + i*256; int r = id>>3, kq = (id&7)*4;
            float4 vx = *(const float4*)&x[(size_t)(row0+r)*256 + k0+kq];
            int k = k0+kq;
            float v0 = vx.x*sc[k]+sh[k],   v1 = vx.y*sc[k+1]+sh[k+1];
            float v2 = vx.z*sc[k+2]+sh[k+2], v3 = vx.w*sc[k+3]+sh[k+3];
            ushort4 hi, lo;
            splitf(v0,hi.x,lo.x); splitf(v1,hi.y,lo.y);
            splitf(v2,hi.z,lo.z); splitf(v3,hi.w,lo.w);
            *(ushort4*)&sAh[r*40+kq] = hi;
            *(ushort4*)&sAl[r*40+kq] = lo;
        }
        #pragma unroll
        for(int i=0;i<8;i++){                       // B: W1t hi/lo [256][32]
            int id = tid + i*256; int plane = id>>10, cid = id&1023;
            int r = cid>>2, c = cid&3;
            const short* src = (plane? w1tl : w1th) + (size_t)r*256 + k0 + c*8;
            short* dst = (plane? sBl : sBh) + r*40 + c*8;
            *(bf16x8*)dst = *(const bf16x8*)src;
        }
        __syncthreads();
        bf16x8 ah[2], al[2];
        #pragma unroll
        for(int tm=0;tm<2;tm++){
            ah[tm] = *(const bf16x8*)&sAh[(m0w+tm*16+ln)*40 + quad*8];
            al[tm] = *(const bf16x8*)&sAl[(m0w+tm*16+ln)*40 + quad*8];
        }
        #pragma unroll
        for(int tn=0;tn<8;tn++){
            bf16x8 bh = *(const bf16x8*)&sBh[(n0b+tn*16+ln)*40 + quad*8];
            bf16x8 bl = *(const bf16x8*)&sBl[(n0b+tn*16+ln)*40 + quad*8];
            #pragma unroll
            for(int tm=0;tm<2;tm++){
                acc[tm][tn] = __builtin_amdgcn_mfma_f32_16x16x32_bf16(al[tm], bh, acc[tm][tn], 0,0,0);
                acc[tm][tn] = __builtin_amdgcn_mfma_f32_16x16x32_bf16(ah[tm], bl, acc[tm][tn], 0,0,0);
                acc[tm][tn] = __builtin_amdgcn_mfma_f32_16x16x32_bf16(ah[tm], bh, acc[tm][tn], 0,0,0);
            }
        }
        __syncthreads();
    }
    #pragma unroll
    for(int tn=0;tn<8;tn++){
        int col = n0b + tn*16 + ln;
        float bias = b1[col];
        #pragma unroll
        for(int tm=0;tm<2;tm++){
            int rowb = row0 + m0w + tm*16 + quad*4;
            #pragma unroll
            for(int r=0;r<4;r++){
                float hv = gelu_f(acc[tm][tn][r] + bias);
                unsigned short hi, lo;
                splitf(hv, hi, lo);
                h1h[(size_t)(rowb+r)*256 + col] = hi;
                h1l[(size_t)(rowb+r)*256 + col] = lo;
            }
        }
    }
    // ---- edge scatter (no barrier after: drains at kernel end) -------------
    int ebase = blockIdx.x*2048;
    #pragma unroll
    for(int i=0;i<8;i++){
        int e = ebase + i*256 + tid;
        int s = ei[e], d = ei[Ee+e];
        if((s>>11) == (d>>11)){
            int ld = d & (Nn-1);
            atomicOr(&mask[(size_t)s*64 + (ld>>5)], 1u<<(ld&31));
        }
    }
}

// ------ Kernel 3: h2=gelu(h1@W2+b2) (split MFMA); logits+argmax in-block ----
// grid 512 (64 rows each), N=128. 4 waves, wave=32m x 64n.
__global__ __launch_bounds__(256) void gemm23_mfma(
    const unsigned short* __restrict__ h1h, const unsigned short* __restrict__ h1l,
    const short* __restrict__ w2th, const short* __restrict__ w2tl,
    const float* __restrict__ b2, const float* __restrict__ W3,
    const float* __restrict__ b3, int* __restrict__ ids)
{
    __shared__ short sAh[64*40], sAl[64*40];
    __shared__ short sBh[128*40], sBl[128*40];
    __shared__ float h2s[64*132];
    __shared__ float lgs[64*20];
    int tid = threadIdx.x;
    int row0 = blockIdx.x*64;
    int lane = tid&63, w = tid>>6;
    int ln = lane&15, quad = lane>>4;
    int m0w = (w&1)*32, n0w = (w>>1)*64;
    f32x4 acc[2][4];
    #pragma unroll
    for(int i=0;i<2;i++)
        #pragma unroll
        for(int j=0;j<4;j++) acc[i][j] = (f32x4){0.f,0.f,0.f,0.f};
    for(int k0=0;k0<256;k0+=32){
        #pragma unroll
        for(int i=0;i<2;i++){                       // A: h1 planes, pure copy
            int id = tid + i*256; int plane = id>>8, cid = id&255;
            int r = cid>>2, c = cid&3;
            const unsigned short* src = (plane? h1l : h1h)
                                        + (size_t)(row0+r)*256 + k0 + c*8;
            short* dst = (plane? sAl : sAh) + r*40 + c*8;
            *(bf16x8*)dst = *(const bf16x8*)src;
        }
        #pragma unroll
        for(int i=0;i<4;i++){
            int id = tid + i*256; int plane = id>>9, cid = id&511;
            int r = cid>>2, c = cid&3;
            const short* src = (plane? w2tl : w2th) + (size_t)r*256 + k0 + c*8;
            short* dst = (plane? sBl : sBh) + r*40 + c*8;
            *(bf16x8*)dst = *(const bf16x8*)src;
        }
        __syncthreads();
        bf16x8 ah[2], al[2];
        #pragma unroll
        for(int tm=0;tm<2;tm++){
            ah[tm] = *(const bf16x8*)&sAh[(m0w+tm*16+ln)*40 + quad*8];
            al[tm] = *(const bf16x8*)&sAl[(m0w+tm*16+ln)*40 + quad*8];
        }
        #pragma unroll
        for(int tn=0;tn<4;tn++){
            bf16x8 bh = *(const bf16x8*)&sBh[(n0w+tn*16+ln)*40 + quad*8];
            bf16x8 bl = *(const bf16x8*)&sBl[(n0w+tn*16+ln)*40 + quad*8];
            #pragma unroll
            for(int tm=0;tm<2;tm++){
                acc[tm][tn] = __builtin_amdgcn_mfma_f32_16x16x32_bf16(al[tm], bh, acc[tm][tn], 0,0,0);
                acc[tm][tn] = __builtin_amdgcn_mfma_f32_16x16x32_bf16(ah[tm], bl, acc[tm][tn], 0,0,0);
                acc[tm][tn] = __builtin_amdgcn_mfma_f32_16x16x32_bf16(ah[tm], bh, acc[tm][tn], 0,0,0);
            }
        }
        __syncthreads();
    }
    #pragma unroll
    for(int tn=0;tn<4;tn++){
        int col = n0w + tn*16 + ln;
        float bias = b2[col];
        #pragma unroll
        for(int tm=0;tm<2;tm++){
            int rb = m0w + tm*16 + quad*4;
            #pragma unroll
            for(int r=0;r<4;r++)
                h2s[(rb+r)*132 + col] = gelu_f(acc[tm][tn][r] + bias);
        }
    }
    float* w3s = (float*)sBh;                       // 2560 f32 = 10240 B fits
    for(int l=tid;l<2560;l+=256) w3s[l] = W3[l];
    __syncthreads();
    int n = tid>>2, q = tid&3;
    float lg[5] = {};
    #pragma unroll 4
    for(int k=0;k<128;k++){
        float h = h2s[n*132+k];
        #pragma unroll
        for(int a=0;a<5;a++) lg[a] += h*w3s[k*20 + q*5 + a];
    }
    #pragma unroll
    for(int a=0;a<5;a++) lgs[n*20 + q*5 + a] = lg[a] + b3[q*5+a];
    __syncthreads();
    if(tid<64){                                     // numpy argmax: first max wins
        float best = lgs[tid*20]; int bi = 0;
        #pragma unroll
        for(int a=1;a<20;a++){ float v2 = lgs[tid*20+a]; if(v2>best){best=v2;bi=a;} }
        ids[row0+tid] = bi;
    }
}

// ---- Kernel 4: aggregation (LDS-resident v) + hout GEMM + all heads --------
// grid 512 (64 nodes each). 4 waves, wave=32m x 64n for GEMM phases.
__global__ __launch_bounds__(256) void msg3_k(
    const int* __restrict__ ids, const unsigned* __restrict__ mask,
    const float* __restrict__ embed,
    const short* __restrict__ wmth, const short* __restrict__ wmtl,
    const float* __restrict__ b_msg, const float* __restrict__ w_coor,
    const short* __restrict__ a1th, const short* __restrict__ a1tl,
    const float* __restrict__ a1v, const float* __restrict__ A2,
    const float* __restrict__ a2v, const float* __restrict__ dalpha,
    const float* __restrict__ dw, const float* __restrict__ db,
    const float* __restrict__ coords, float* __restrict__ out_ang,
    float* __restrict__ out_z, float* __restrict__ out_co)
{
    __shared__ unsigned short v_bf[64*136];    // v bf16 (row pad 136)
    __shared__ unsigned short houts[64*136];   // hout bf16; later t1s [64][104]
    // arena: phase0 {ind 5120 | sid 2048 | emb 10240} -> GEMM {sBh 10240|sBl 10240}
    __shared__ __align__(16) unsigned char arena[20480];
    __shared__ float s_bm[128], s_wc[384], s_A2[624], s_a1[104];
    __shared__ float s_dyt[16], s_a2[8];

    unsigned*       ind = (unsigned*)arena;
    unsigned char*  sid = arena + 5120;
    float*          emb = (float*)(arena + 7168);
    short*          sBh = (short*)arena;
    short*          sBl = (short*)(arena + 10240);

    int tid = threadIdx.x;
    int row0 = blockIdx.x*64;
    int g = blockIdx.x>>5, tile = blockIdx.x&31;
    int lane = tid&63, w = tid>>6;
    int ln = lane&15, quad = lane>>4;
    int m0w = (w&1)*32, n0w = (w>>1)*64;

    // --- head constants + phase0 cooperative loads --------------------------
    for(int l=tid;l<NATOMS*128;l+=256) emb[l] = embed[l];
    #pragma unroll
    for(int i=0;i<8;i++){ int j = tid + i*256; sid[j] = (unsigned char)ids[g*Nn + j]; }
    if(tid<128) s_bm[tid] = b_msg[tid];
    if(tid<104) s_a1[tid] = (tid<ENCH) ? a1v[tid] : 0.f;
    for(int l=tid;l<384;l+=256) s_wc[l] = w_coor[l];
    for(int l=tid;l<624;l+=256) s_A2[l] = (l<600) ? A2[l] : 0.f;
    if(tid==0)  s_dyt[0] = dalpha[0];
    if(tid<6){ s_dyt[1+tid] = dw[tid]; s_dyt[8+tid] = db[tid]; }
    if(tid<8)  s_a2[tid] = (tid<6) ? a2v[tid] : 0.f;

    int node = tid>>2, p = tid&3;
    const unsigned* mrow = &mask[((size_t)(row0 + node))*64 + p*16];
    uint4 mm0 = *(const uint4*)&mrow[0];
    uint4 mm1 = *(const uint4*)&mrow[4];
    uint4 mm2 = *(const uint4*)&mrow[8];
    uint4 mm3 = *(const uint4*)&mrow[12];
    __syncthreads();

    // --- per-atom indicator bitmasks via ballot -----------------------------
    for(int wp=w; wp<32; wp+=4){
        int a = sid[wp*64 + lane];
        #pragma unroll
        for(int atom=0; atom<NATOMS; atom++){
            unsigned long long bm = __ballot(a==atom);
            if(lane<2) ind[atom*64 + wp*2 + lane] = (unsigned)(bm >> (32*lane));
        }
    }
    __syncthreads();

    // --- per-node counts: popcount(mask & ind), 4-lane split ----------------
    unsigned mw[16];
    *(uint4*)&mw[0]=mm0; *(uint4*)&mw[4]=mm1; *(uint4*)&mw[8]=mm2; *(uint4*)&mw[12]=mm3;
    int degi = 0;
    #pragma unroll
    for(int w2=0;w2<16;w2++) degi += __popc(mw[w2]);
    float cnt[NATOMS];
    #pragma unroll
    for(int a=0;a<NATOMS;a++){
        int c = 0;
        const unsigned* ia = &ind[a*64 + p*16];
        #pragma unroll
        for(int w2=0;w2<16;w2++) c += __popc(mw[w2] & ia[w2]);
        cnt[a] = (float)c;
    }
    #pragma unroll
    for(int a=0;a<NATOMS;a++){
        cnt[a] += __shfl_xor(cnt[a],1,64);
        cnt[a] += __shfl_xor(cnt[a],2,64);
    }
    float deg = (float)degi;
    deg += __shfl_xor(deg,1,64);
    deg += __shfl_xor(deg,2,64);

    // --- v = emb[own] + (sum_a cnt_a emb_a)/max(deg,1) -> LDS bf16 ----------
    {
        float inv = 1.0f / fmaxf(deg, 1.0f);
        int oid = sid[tile*64 + node];
        int d0 = p*32;
        float vv[32];
        #pragma unroll
        for(int d=0;d<32;d++) vv[d]=0.f;
        #pragma unroll
        for(int a=0;a<NATOMS;a++){
            float ca = cnt[a];
            const float* ea = &emb[a*128 + d0];
            #pragma unroll
            for(int d=0;d<32;d+=4){
                float4 e = *(const float4*)&ea[d];
                vv[d]+=ca*e.x; vv[d+1]+=ca*e.y; vv[d+2]+=ca*e.z; vv[d+3]+=ca*e.w;
            }
        }
        const float* eo = &emb[oid*128 + d0];
        unsigned short* dst = &v_bf[node*136 + d0];
        #pragma unroll
        for(int d=0;d<32;d+=4){
            float4 e = *(const float4*)&eo[d];
            ushort4 o;
            o.x = f2b(e.x + vv[d]*inv);
            o.y = f2b(e.y + vv[d+1]*inv);
            o.z = f2b(e.z + vv[d+2]*inv);
            o.w = f2b(e.w + vv[d+3]*inv);
            *(ushort4*)&dst[d] = o;
        }
    }
    __syncthreads();     // v complete; emb/ind dead -> arena becomes sB

    // ---- hout = gelu(v @ W_msg + b), 2-term W split, A direct from v_bf ----
    f32x4 acc[2][4];
    #pragma unroll
    for(int i=0;i<2;i++)
        #pragma unroll
        for(int j=0;j<4;j++) acc[i][j] = (f32x4){0.f,0.f,0.f,0.f};
    for(int k0=0;k0<128;k0+=32){
        #pragma unroll
        for(int i=0;i<4;i++){                           // B: Wmsg_t [128][32]
            int id = tid + i*256; int plane = id>>9, cid = id&511;
            int r = cid>>2, c = cid&3;
            const short* src = (plane? wmtl : wmth) + (size_t)r*128 + k0 + c*8;
            short* dst = (plane? sBl : sBh) + r*40 + c*8;
            *(bf16x8*)dst = *(const bf16x8*)src;
        }
        __syncthreads();
        bf16x8 av[2];
        #pragma unroll
        for(int tm=0;tm<2;tm++)
            av[tm] = *(const bf16x8*)&v_bf[(m0w+tm*16+ln)*136 + k0 + quad*8];
        #pragma unroll
        for(int tn=0;tn<4;tn++){
            bf16x8 bh = *(const bf16x8*)&sBh[(n0w+tn*16+ln)*40 + quad*8];
            bf16x8 bl = *(const bf16x8*)&sBl[(n0w+tn*16+ln)*40 + quad*8];
            #pragma unroll
            for(int tm=0;tm<2;tm++){
                acc[tm][tn] = __builtin_amdgcn_mfma_f32_16x16x32_bf16(av[tm], bl, acc[tm][tn], 0,0,0);
                acc[tm][tn] = __builtin_amdgcn_mfma_f32_16x16x32_bf16(av[tm], bh, acc[tm][tn], 0,0,0);
            }
        }
        __syncthreads();
    }
    // epilogue: z fp32 + hout bf16 to LDS
    #pragma unroll
    for(int tn=0;tn<4;tn++){
        int col = n0w + tn*16 + ln;
        float bias = s_bm[col];
        #pragma unroll
        for(int tm=0;tm<2;tm++){
            int mb2 = m0w + tm*16 + quad*4;
            #pragma unroll
            for(int r=0;r<4;r++){
                float hv = gelu_f(acc[tm][tn][r] + bias);
                out_z[(size_t)(row0+mb2+r)*128 + col] = hv;
                houts[(mb2+r)*136 + col] = f2b(hv);
            }
        }
    }
    __syncthreads();

    // ---- coors: 4-lane k-split dot with w_coor -----------------------------
    {
        float d0=0.f, d1=0.f, d2=0.f;
        int kb = p*32;
        #pragma unroll
        for(int k=0;k<32;k+=4){
            ushort4 hv = *(const ushort4*)&houts[node*136 + kb + k];
            float h0=b2f(hv.x),h1=b2f(hv.y),h2=b2f(hv.z),h3=b2f(hv.w);
            const float* wc = &s_wc[(kb+k)*3];
            d0 += h0*wc[0]+h1*wc[3]+h2*wc[6]+h3*wc[9];
            d1 += h0*wc[1]+h1*wc[4]+h2*wc[7]+h3*wc[10];
            d2 += h0*wc[2]+h1*wc[5]+h2*wc[8]+h3*wc[11];
        }
        d0 += __shfl_xor(d0,1,64); d0 += __shfl_xor(d0,2,64);
        d1 += __shfl_xor(d1,1,64); d1 += __shfl_xor(d1,2,64);
        d2 += __shfl_xor(d2,1,64); d2 += __shfl_xor(d2,2,64);
        if(p==0){
            size_t o = (size_t)(row0+node)*3;
            out_co[o+0] = coords[o+0] + tanhf(d0);
            out_co[o+1] = coords[o+1] + tanhf(d1);
            out_co[o+2] = coords[o+2] + tanhf(d2);
        }
    }

    // ---- t1 = gelu(hout @ A1 + a1), 2-term split, N=128 (cols>=100 zero) ---
    f32x4 acc2[2][4];
    #pragma unroll
    for(int i=0;i<2;i++)
        #pragma unroll
        for(int j=0;j<4;j++) acc2[i][j] = (f32x4){0.f,0.f,0.f,0.f};
    for(int k0=0;k0<128;k0+=32){
        __syncthreads();                    // protect sB reuse across iters
        #pragma unroll
        for(int i=0;i<4;i++){
            int id = tid + i*256; int plane = id>>9, cid = id&511;
            int r = cid>>2, c = cid&3;
            const short* src = (plane? a1tl : a1th) + (size_t)r*128 + k0 + c*8;
            short* dst = (plane? sBl : sBh) + r*40 + c*8;
            *(bf16x8*)dst = *(const bf16x8*)src;
        }
        __syncthreads();
        bf16x8 ah[2];
        #pragma unroll
        for(int tm=0;tm<2;tm++)
            ah[tm] = *(const bf16x8*)&houts[(m0w+tm*16+ln)*136 + k0 + quad*8];
        #pragma unroll
        for(int tn=0;tn<4;tn++){
            bf16x8 bh = *(const bf16x8*)&sBh[(n0w+tn*16+ln)*40 + quad*8];
            bf16x8 bl = *(const bf16x8*)&sBl[(n0w+tn*16+ln)*40 + quad*8];
            #pragma unroll
            for(int tm=0;tm<2;tm++){
                acc2[tm][tn] = __builtin_amdgcn_mfma_f32_16x16x32_bf16(ah[tm], bl, acc2[tm][tn], 0,0,0);
                acc2[tm][tn] = __builtin_amdgcn_mfma_f32_16x16x32_bf16(ah[tm], bh, acc2[tm][tn], 0,0,0);
            }
        }
    }
    __syncthreads();                        // houts reads done -> reuse as t1s
    unsigned short* t1s = houts;            // [64][104]
    #pragma unroll
    for(int tn=0;tn<4;tn++){
        int col = n0w + tn*16 + ln;
        if(col < 104){
            float bias = s_a1[col];
            #pragma unroll
            for(int tm=0;tm<2;tm++){
                int mb2 = m0w + tm*16 + quad*4;
                #pragma unroll
                for(int r=0;r<4;r++)
                    t1s[(mb2+r)*104 + col] = f2b(gelu_f(acc2[tm][tn][r] + bias));
            }
        }
    }
    __syncthreads();

    // ---- t2 = gelu(t1@A2+a2); DyT; angles ----------------------------------
    {
        int g0 = (p<2) ? p*7 : 14+(p-2)*6;
        int gcount = (p<2) ? 7 : 6;
        float s[6] = {0.f,0.f,0.f,0.f,0.f,0.f};
        for(int gg=0; gg<gcount; gg++){
            int kb = (g0+gg)*4;
            ushort4 tv = *(const ushort4*)&t1s[node*104 + kb];
            float u0=b2f(tv.x), u1=b2f(tv.y), u2=b2f(tv.z), u3=b2f(tv.w);
            #pragma unroll
            for(int j=0;j<6;j++)
                s[j] += u0*s_A2[kb*6+j] + u1*s_A2[(kb+1)*6+j]
                      + u2*s_A2[(kb+2)*6+j] + u3*s_A2[(kb+3)*6+j];
        }
        #pragma unroll
        for(int j=0;j<6;j++){ s[j]+=__shfl_xor(s[j],1,64); s[j]+=__shfl_xor(s[j],2,64); }
        if(p<2){
            size_t o = (size_t)(row0+node)*6 + p*3;
            #pragma unroll
            for(int jj=0;jj<3;jj++){
                int j = p*3+jj;
                float t2v = gelu_f(s[j] + s_a2[j]);
                float uu = tanhf(s_dyt[0]*t2v)*s_dyt[1+j] + s_dyt[8+j];
                out_ang[o+jj] = tanhf(uu);
            }
        }
    }
}

// ---------------------------------------------------------------------------
extern "C" void kernel_launch(void* const* d_in, const int* in_sizes, int n_in,
                              void* d_out, int out_size, void* d_ws, size_t ws_size,
                              hipStream_t stream) {
    const float* x      = (const float*)d_in[0];
    const float* coords = (const float*)d_in[1];
    const int*   ei     = (const int*)d_in[2];
    const float* gamma  = (const float*)d_in[4];
    const float* beta   = (const float*)d_in[5];
    const float* W1     = (const float*)d_in[6];
    const float* b1     = (const float*)d_in[7];
    const float* W2     = (const float*)d_in[8];
    const float* b2     = (const float*)d_in[9];
    const float* W3     = (const float*)d_in[10];
    const float* b3     = (const float*)d_in[11];
    const float* embed  = (const float*)d_in[12];
    const float* W_msg  = (const float*)d_in[13];
    const float* b_msg  = (const float*)d_in[14];
    const float* w_coor = (const float*)d_in[15];
    const float* A1     = (const float*)d_in[16];
    const float* a1v    = (const float*)d_in[17];
    const float* A2     = (const float*)d_in[18];
    const float* a2v    = (const float*)d_in[19];
    const float* dalpha = (const float*)d_in[20];
    const float* dw     = (const float*)d_in[21];
    const float* db     = (const float*)d_in[22];

    // ws layout (~44 MB peak):
    //  0    : ids   (128 KB)
    //  128K : stats (2 KB)
    //  256K : weight planes (512 KB)
    //  1M   : mask  (8 MB)
    //  10M  : h1h u16 (16.78 MB)
    //  27M  : h1l u16 (16.78 MB)
    char* ws = (char*)d_ws;
    int*      ids   = (int*)ws;
    float*    stats = (float*)(ws + 131072);
    short*    w1th  = (short*)(ws + 262144);
    short*    w1tl  = w1th + 65536;
    short*    w2th  = w1tl + 65536;
    short*    w2tl  = w2th + 32768;
    short*    wmth  = w2tl + 32768;
    short*    wmtl  = wmth + 16384;
    short*    a1th  = wmtl + 16384;
    short*    a1tl  = a1th + 16384;
    unsigned* mask  = (unsigned*)(ws + (1<<20));
    unsigned short* h1h = (unsigned short*)(ws + (size_t)10*1048576);
    unsigned short* h1l = (unsigned short*)(ws + (size_t)27*1048576);

    float* out_ang = (float*)d_out;
    float* out_z   = out_ang + (size_t)NT*OUTC;
    float* out_co  = out_z   + (size_t)NT*DIMd;

    hipMemsetAsync(stats, 0, 2*INC*sizeof(float), stream);
    hipMemsetAsync(mask, 0, (size_t)NT*64*sizeof(unsigned), stream);
    prep0_k<<<320, 256, 0, stream>>>(x, stats, W1, W2, W_msg, A1,
        w1th, w1tl, w2th, w2tl, wmth, wmtl, a1th, a1tl);
    gemm1_adj_k<<<512, 256, 0, stream>>>(x, stats, gamma, beta, w1th, w1tl, b1,
        h1h, h1l, ei, mask);
    gemm23_mfma<<<512, 256, 0, stream>>>(h1h, h1l, w2th, w2tl, b2, W3, b3, ids);
    msg3_k<<<512, 256, 0, stream>>>(ids, mask, embed, wmth, wmtl, b_msg, w_coor,
        a1th, a1tl, a1v, A2, a2v, dalpha, dw, db, coords, out_ang, out_z, out_co);
}

// Round 5
// 253.899 us; speedup vs baseline: 1.0709x; 1.0709x over previous
//
#include <hip/hip_runtime.h>
#include <hip/hip_bf16.h>
#include <math.h>

// Problem constants (match reference)
#define Bg 16
#define Nn 2048
#define Ee (1<<20)
#define NT (Bg*Nn)
#define INC 256
#define DIMd 128
#define OUTC 6
#define ENCH 100
#define NATOMS 20
#define BINCAP 3072   // per-bin edge capacity: mean 2048, sigma~44 -> +23 sigma

typedef __attribute__((ext_vector_type(8))) short bf16x8;
typedef __attribute__((ext_vector_type(4))) float f32x4;

__device__ __forceinline__ float gelu_f(float x){
    return 0.5f*x*(1.0f+erff(x*0.70710678118654752440f));
}
__device__ __forceinline__ unsigned short f2b(float f){
    __hip_bfloat16 h = __float2bfloat16(f);
    return *(unsigned short*)&h;
}
__device__ __forceinline__ float b2f(unsigned short u){
    unsigned v = ((unsigned)u)<<16;
    return __uint_as_float(v);
}
// split fp32 into bf16 hi + bf16 lo (v ~= hi + lo, dropped residual ~2^-18 rel)
__device__ __forceinline__ void splitf(float v, unsigned short& hi, unsigned short& lo){
    unsigned short h = f2b(v);
    hi = h; lo = f2b(v - b2f(h));
}

// ---- Kernel 1: prep0 = BN stats (blocks 0..255) + weight split (256..319) --
__global__ __launch_bounds__(256) void prep0_k(const float* __restrict__ x,
    float* __restrict__ stats, const float* __restrict__ W1,
    const float* __restrict__ W2, const float* __restrict__ Wm,
    const float* __restrict__ A1, short* __restrict__ w1th, short* __restrict__ w1tl,
    short* __restrict__ w2th, short* __restrict__ w2tl,
    short* __restrict__ wmth, short* __restrict__ wmtl,
    short* __restrict__ a1th, short* __restrict__ a1tl)
{
    int bx = blockIdx.x, tid = threadIdx.x;
    if(bx < 256){
        int c = tid;
        int r0 = bx * 128;
        const float* p = x + (size_t)r0*INC + c;
        float s = 0.f, s2 = 0.f;
        #pragma unroll 8
        for(int r=0;r<128;r++){ float v = p[(size_t)r*INC]; s += v; s2 += v*v; }
        atomicAdd(&stats[c], s);
        atomicAdd(&stats[INC+c], s2);
    } else {
        int gid = (bx-256)*256 + tid;             // 64 blocks -> 16384 threads
        unsigned short hi, lo;
        for(int l=gid;l<65536;l+=16384){ int n=l>>8,k=l&255;
            splitf(W1[(size_t)k*256+n],hi,lo); w1th[l]=(short)hi; w1tl[l]=(short)lo; }
        for(int l=gid;l<32768;l+=16384){ int n=l>>8,k=l&255;
            splitf(W2[(size_t)k*128+n],hi,lo); w2th[l]=(short)hi; w2tl[l]=(short)lo; }
        for(int l=gid;l<16384;l+=16384){ int n=l>>7,k=l&127;
            splitf(Wm[(size_t)k*128+n],hi,lo); wmth[l]=(short)hi; wmtl[l]=(short)lo; }
        for(int l=gid;l<16384;l+=16384){ int n=l>>7,k=l&127;
            float v=(n<ENCH)? A1[(size_t)k*ENCH+n] : 0.f;
            splitf(v,hi,lo); a1th[l]=(short)hi; a1tl[l]=(short)lo; }
    }
}

// ---- Kernel 2: h1 = gelu(BN(x)@W1+b1), 64x256 tile, 3-term split MFMA ------
// Register-prefetched double-buffer staging. Blocks 0..127 additionally run
// the edge bucket-scatter tail (LDS histogram -> bump-alloc -> plain stores:
// avoids 1M memory-side atomicOr RMWs entirely).
__global__ __launch_bounds__(256) void gemm1_scat_k(const float* __restrict__ x,
    const float* __restrict__ stats, const float* __restrict__ gamma,
    const float* __restrict__ beta, const short* __restrict__ w1th,
    const short* __restrict__ w1tl, const float* __restrict__ b1,
    unsigned short* __restrict__ h1h, unsigned short* __restrict__ h1l,
    const int* __restrict__ ei, unsigned* __restrict__ ecnt,
    unsigned* __restrict__ earena)
{
    __shared__ float sc[256], sh[256];
    __shared__ short sAh[64*40], sAl[64*40];     // pad 40: 16B-aligned frags
    __shared__ short sBh[256*40], sBl[256*40];
    int tid = threadIdx.x;
    {
        float mu  = stats[tid]*(1.0f/NT);
        float var = stats[256+tid]*(1.0f/NT) - mu*mu;
        float s = gamma[tid]/sqrtf(var + 1e-5f);
        sc[tid] = s; sh[tid] = beta[tid] - mu*s;
    }
    int row0 = blockIdx.x*64;
    int lane = tid&63, w = tid>>6;
    int ln = lane&15, quad = lane>>4;
    int m0w = (w&1)*32, n0b = (w>>1)*128;
    f32x4 acc[2][8];
    #pragma unroll
    for(int i=0;i<2;i++)
        #pragma unroll
        for(int j=0;j<8;j++) acc[i][j] = (f32x4){0.f,0.f,0.f,0.f};

    float4 xa[2]; bf16x8 wb[8];
    #pragma unroll
    for(int i=0;i<2;i++){ int id=tid+i*256; int r=id>>3,kq=(id&7)*4;
        xa[i] = *(const float4*)&x[(size_t)(row0+r)*256 + kq]; }
    #pragma unroll
    for(int i=0;i<8;i++){ int id=tid+i*256; int plane=id>>10,cid=id&1023;
        int r=cid>>2,c=cid&3;
        wb[i] = *(const bf16x8*)((plane? w1tl:w1th) + (size_t)r*256 + c*8); }
    __syncthreads();
    for(int k0=0;k0<256;k0+=32){
        #pragma unroll
        for(int i=0;i<2;i++){                       // A: BN(x) split -> LDS
            int id = tid + i*256; int r = id>>3, kq = (id&7)*4;
            int k = k0+kq;
            float v0 = xa[i].x*sc[k]+sh[k],   v1 = xa[i].y*sc[k+1]+sh[k+1];
            float v2 = xa[i].z*sc[k+2]+sh[k+2], v3 = xa[i].w*sc[k+3]+sh[k+3];
            ushort4 hi, lo;
            splitf(v0,hi.x,lo.x); splitf(v1,hi.y,lo.y);
            splitf(v2,hi.z,lo.z); splitf(v3,hi.w,lo.w);
            *(ushort4*)&sAh[r*40+kq] = hi;
            *(ushort4*)&sAl[r*40+kq] = lo;
        }
        #pragma unroll
        for(int i=0;i<8;i++){                       // B regs -> LDS
            int id = tid + i*256; int plane = id>>10, cid = id&1023;
            int r = cid>>2, c = cid&3;
            *(bf16x8*)((plane? sBl : sBh) + r*40 + c*8) = wb[i];
        }
        __syncthreads();
        if(k0 < 224){                               // prefetch next tile
            #pragma unroll
            for(int i=0;i<2;i++){ int id=tid+i*256; int r=id>>3,kq=(id&7)*4;
                xa[i] = *(const float4*)&x[(size_t)(row0+r)*256 + k0+32+kq]; }
            #pragma unroll
            for(int i=0;i<8;i++){ int id=tid+i*256; int plane=id>>10,cid=id&1023;
                int r=cid>>2,c=cid&3;
                wb[i] = *(const bf16x8*)((plane? w1tl:w1th) + (size_t)r*256 + k0+32 + c*8); }
        }
        bf16x8 ah[2], al[2];
        #pragma unroll
        for(int tm=0;tm<2;tm++){
            ah[tm] = *(const bf16x8*)&sAh[(m0w+tm*16+ln)*40 + quad*8];
            al[tm] = *(const bf16x8*)&sAl[(m0w+tm*16+ln)*40 + quad*8];
        }
        #pragma unroll
        for(int tn=0;tn<8;tn++){
            bf16x8 bh = *(const bf16x8*)&sBh[(n0b+tn*16+ln)*40 + quad*8];
            bf16x8 bl = *(const bf16x8*)&sBl[(n0b+tn*16+ln)*40 + quad*8];
            #pragma unroll
            for(int tm=0;tm<2;tm++){
                acc[tm][tn] = __builtin_amdgcn_mfma_f32_16x16x32_bf16(al[tm], bh, acc[tm][tn], 0,0,0);
                acc[tm][tn] = __builtin_amdgcn_mfma_f32_16x16x32_bf16(ah[tm], bl, acc[tm][tn], 0,0,0);
                acc[tm][tn] = __builtin_amdgcn_mfma_f32_16x16x32_bf16(ah[tm], bh, acc[tm][tn], 0,0,0);
            }
        }
        __syncthreads();
    }
    #pragma unroll
    for(int tn=0;tn<8;tn++){
        int col = n0b + tn*16 + ln;
        float bias = b1[col];
        #pragma unroll
        for(int tm=0;tm<2;tm++){
            int rowb = row0 + m0w + tm*16 + quad*4;
            #pragma unroll
            for(int r=0;r<4;r++){
                float hv = gelu_f(acc[tm][tn][r] + bias);
                unsigned short hi, lo;
                splitf(hv, hi, lo);
                h1h[(size_t)(rowb+r)*256 + col] = hi;
                h1l[(size_t)(rowb+r)*256 + col] = lo;
            }
        }
    }
    // ---- edge bucket-scatter tail (blocks 0..127; 8192 edges each) --------
    if(blockIdx.x < 128){
        __syncthreads();                     // GEMM LDS dead -> reuse sAh
        unsigned* lcnt  = (unsigned*)sAh;    // 512 u32
        unsigned* gbase = ((unsigned*)sAh) + 512;
        for(int l=tid; l<512; l+=256) lcnt[l] = 0;
        __syncthreads();
        int ebase = blockIdx.x * 8192;
        #pragma unroll 8
        for(int i=0;i<32;i++){
            int e = ebase + i*256 + tid;
            int s = ei[e], d = ei[Ee+e];
            if((s>>11)==(d>>11)) atomicAdd(&lcnt[s>>6], 1u);
        }
        __syncthreads();
        for(int l=tid; l<512; l+=256){
            unsigned c = lcnt[l];
            gbase[l] = c ? atomicAdd(&ecnt[l], c) : 0u;
            lcnt[l] = 0;
        }
        __syncthreads();
        #pragma unroll 8
        for(int i=0;i<32;i++){
            int e = ebase + i*256 + tid;
            int s = ei[e], d = ei[Ee+e];
            if((s>>11)==(d>>11)){
                int bin = s>>6;
                unsigned r = atomicAdd(&lcnt[bin], 1u);
                unsigned pos = gbase[bin] + r;
                if(pos < BINCAP)
                    earena[(size_t)bin*BINCAP + pos] =
                        ((unsigned)(s&63)<<11) | (unsigned)(d&2047);
            }
        }
    }
}

// ------ Kernel 3: h2=gelu(h1@W2+b2) (split MFMA); logits+argmax in-block ----
// grid 512 (64 rows each), N=128. 4 waves, wave=32m x 64n. Prefetched staging.
__global__ __launch_bounds__(256) void gemm23_mfma(
    const unsigned short* __restrict__ h1h, const unsigned short* __restrict__ h1l,
    const short* __restrict__ w2th, const short* __restrict__ w2tl,
    const float* __restrict__ b2, const float* __restrict__ W3,
    const float* __restrict__ b3, int* __restrict__ ids)
{
    __shared__ short sAh[64*40], sAl[64*40];
    __shared__ short sBh[128*40], sBl[128*40];
    __shared__ float h2s[64*132];
    __shared__ float lgs[64*20];
    int tid = threadIdx.x;
    int row0 = blockIdx.x*64;
    int lane = tid&63, w = tid>>6;
    int ln = lane&15, quad = lane>>4;
    int m0w = (w&1)*32, n0w = (w>>1)*64;
    f32x4 acc[2][4];
    #pragma unroll
    for(int i=0;i<2;i++)
        #pragma unroll
        for(int j=0;j<4;j++) acc[i][j] = (f32x4){0.f,0.f,0.f,0.f};

    bf16x8 ha[2], wb[4];
    #pragma unroll
    for(int i=0;i<2;i++){ int id=tid+i*256; int plane=id>>8,cid=id&255;
        int r=cid>>2,c=cid&3;
        ha[i] = *(const bf16x8*)((const short*)(plane? h1l : h1h)
                                 + (size_t)(row0+r)*256 + c*8); }
    #pragma unroll
    for(int i=0;i<4;i++){ int id=tid+i*256; int plane=id>>9,cid=id&511;
        int r=cid>>2,c=cid&3;
        wb[i] = *(const bf16x8*)((plane? w2tl:w2th) + (size_t)r*256 + c*8); }
    for(int k0=0;k0<256;k0+=32){
        #pragma unroll
        for(int i=0;i<2;i++){
            int id = tid + i*256; int plane = id>>8, cid = id&255;
            int r = cid>>2, c = cid&3;
            *(bf16x8*)((plane? sAl : sAh) + r*40 + c*8) = ha[i];
        }
        #pragma unroll
        for(int i=0;i<4;i++){
            int id = tid + i*256; int plane = id>>9, cid = id&511;
            int r = cid>>2, c = cid&3;
            *(bf16x8*)((plane? sBl : sBh) + r*40 + c*8) = wb[i];
        }
        __syncthreads();
        if(k0 < 224){
            #pragma unroll
            for(int i=0;i<2;i++){ int id=tid+i*256; int plane=id>>8,cid=id&255;
                int r=cid>>2,c=cid&3;
                ha[i] = *(const bf16x8*)((const short*)(plane? h1l : h1h)
                                         + (size_t)(row0+r)*256 + k0+32 + c*8); }
            #pragma unroll
            for(int i=0;i<4;i++){ int id=tid+i*256; int plane=id>>9,cid=id&511;
                int r=cid>>2,c=cid&3;
                wb[i] = *(const bf16x8*)((plane? w2tl:w2th) + (size_t)r*256 + k0+32 + c*8); }
        }
        bf16x8 ah[2], al[2];
        #pragma unroll
        for(int tm=0;tm<2;tm++){
            ah[tm] = *(const bf16x8*)&sAh[(m0w+tm*16+ln)*40 + quad*8];
            al[tm] = *(const bf16x8*)&sAl[(m0w+tm*16+ln)*40 + quad*8];
        }
        #pragma unroll
        for(int tn=0;tn<4;tn++){
            bf16x8 bh = *(const bf16x8*)&sBh[(n0w+tn*16+ln)*40 + quad*8];
            bf16x8 bl = *(const bf16x8*)&sBl[(n0w+tn*16+ln)*40 + quad*8];
            #pragma unroll
            for(int tm=0;tm<2;tm++){
                acc[tm][tn] = __builtin_amdgcn_mfma_f32_16x16x32_bf16(al[tm], bh, acc[tm][tn], 0,0,0);
                acc[tm][tn] = __builtin_amdgcn_mfma_f32_16x16x32_bf16(ah[tm], bl, acc[tm][tn], 0,0,0);
                acc[tm][tn] = __builtin_amdgcn_mfma_f32_16x16x32_bf16(ah[tm], bh, acc[tm][tn], 0,0,0);
            }
        }
        __syncthreads();
    }
    #pragma unroll
    for(int tn=0;tn<4;tn++){
        int col = n0w + tn*16 + ln;
        float bias = b2[col];
        #pragma unroll
        for(int tm=0;tm<2;tm++){
            int rb = m0w + tm*16 + quad*4;
            #pragma unroll
            for(int r=0;r<4;r++)
                h2s[(rb+r)*132 + col] = gelu_f(acc[tm][tn][r] + bias);
        }
    }
    float* w3s = (float*)sBh;                       // 2560 f32 = 10240 B fits
    for(int l=tid;l<2560;l+=256) w3s[l] = W3[l];
    __syncthreads();
    int n = tid>>2, q = tid&3;
    float lg[5] = {};
    #pragma unroll 4
    for(int k=0;k<128;k++){
        float h = h2s[n*132+k];
        #pragma unroll
        for(int a=0;a<5;a++) lg[a] += h*w3s[k*20 + q*5 + a];
    }
    #pragma unroll
    for(int a=0;a<5;a++) lgs[n*20 + q*5 + a] = lg[a] + b3[q*5+a];
    __syncthreads();
    if(tid<64){                                     // numpy argmax: first max wins
        float best = lgs[tid*20]; int bi = 0;
        #pragma unroll
        for(int a=1;a<20;a++){ float v2 = lgs[tid*20+a]; if(v2>best){best=v2;bi=a;} }
        ids[row0+tid] = bi;
    }
}

// ---- Kernel 4: LDS adjacency rebuild + aggregation + hout GEMM + heads -----
// grid 512 (64 nodes each = bucket blockIdx). 4 waves.
__global__ __launch_bounds__(256) void msg3_k(
    const int* __restrict__ ids, const unsigned* __restrict__ ecnt,
    const unsigned* __restrict__ earena, const float* __restrict__ embed,
    const short* __restrict__ wmth, const short* __restrict__ wmtl,
    const float* __restrict__ b_msg, const float* __restrict__ w_coor,
    const short* __restrict__ a1th, const short* __restrict__ a1tl,
    const float* __restrict__ a1v, const float* __restrict__ A2,
    const float* __restrict__ a2v, const float* __restrict__ dalpha,
    const float* __restrict__ dw, const float* __restrict__ db,
    const float* __restrict__ coords, float* __restrict__ out_ang,
    float* __restrict__ out_z, float* __restrict__ out_co)
{
    __shared__ unsigned short v_bf[64*136];    // v bf16 (row pad 136)
    __shared__ unsigned short houts[64*136];   // hout bf16; later t1s [64][104]
    // arena phase 0/1: lmask u32[4096] | ind u32[1280] | sid u8[2048] | emb f32[2560]
    // GEMM phases:     sBh[10240 B] | sBl[10240 B] (overlays lmask+ind)
    __shared__ __align__(16) unsigned char arena[33792];
    __shared__ float s_bm[128], s_wc[384], s_A2[624], s_a1[104];
    __shared__ float s_dyt[16], s_a2[8];

    unsigned*       lmask = (unsigned*)arena;
    unsigned*       ind   = (unsigned*)(arena + 16384);
    unsigned char*  sid   = arena + 21504;
    float*          emb   = (float*)(arena + 23552);
    short*          sBh   = (short*)arena;
    short*          sBl   = (short*)(arena + 10240);

    int tid = threadIdx.x;
    int bin = blockIdx.x;
    int row0 = bin*64;
    int g = blockIdx.x>>5, tile = blockIdx.x&31;
    int lane = tid&63, w = tid>>6;
    int ln = lane&15, quad = lane>>4;
    int m0w = (w&1)*32, n0w = (w>>1)*64;

    // --- phase 0: constants + emb + sid + zero lmask ------------------------
    for(int l=tid;l<NATOMS*128;l+=256) emb[l] = embed[l];
    #pragma unroll
    for(int i=0;i<8;i++){ int j = tid + i*256; sid[j] = (unsigned char)ids[g*Nn + j]; }
    #pragma unroll
    for(int i=0;i<16;i++) lmask[tid + i*256] = 0;
    if(tid<128) s_bm[tid] = b_msg[tid];
    if(tid<104) s_a1[tid] = (tid<ENCH) ? a1v[tid] : 0.f;
    for(int l=tid;l<384;l+=256) s_wc[l] = w_coor[l];
    for(int l=tid;l<624;l+=256) s_A2[l] = (l<600) ? A2[l] : 0.f;
    if(tid==0)  s_dyt[0] = dalpha[0];
    if(tid<6){ s_dyt[1+tid] = dw[tid]; s_dyt[8+tid] = db[tid]; }
    if(tid<8)  s_a2[tid] = (tid<6) ? a2v[tid] : 0.f;
    int nb = min((int)ecnt[bin], BINCAP);
    __syncthreads();

    // --- phase 1: ballot indicator bitmasks + LDS adjacency build -----------
    for(int wp=w; wp<32; wp+=4){
        int a = sid[wp*64 + lane];
        #pragma unroll
        for(int atom=0; atom<NATOMS; atom++){
            unsigned long long bm = __ballot(a==atom);
            if(lane<2) ind[atom*64 + wp*2 + lane] = (unsigned)(bm >> (32*lane));
        }
    }
    for(int i=tid; i<nb; i+=256){
        unsigned wv = earena[(size_t)bin*BINCAP + i];
        int sl = wv>>11, dl = wv & 2047;
        atomicOr(&lmask[sl*64 + (dl>>5)], 1u<<(dl&31));
    }
    __syncthreads();

    // --- phase 2: per-node counts popcount(lmask & ind), 4-lane split -------
    int node = tid>>2, p = tid&3;
    unsigned mw[16];
    {
        const unsigned* mrow = &lmask[node*64 + p*16];
        *(uint4*)&mw[0]  = *(const uint4*)&mrow[0];
        *(uint4*)&mw[4]  = *(const uint4*)&mrow[4];
        *(uint4*)&mw[8]  = *(const uint4*)&mrow[8];
        *(uint4*)&mw[12] = *(const uint4*)&mrow[12];
    }
    int degi = 0;
    #pragma unroll
    for(int w2=0;w2<16;w2++) degi += __popc(mw[w2]);
    float cnt[NATOMS];
    #pragma unroll
    for(int a=0;a<NATOMS;a++){
        int c = 0;
        const unsigned* ia = &ind[a*64 + p*16];
        #pragma unroll
        for(int w2=0;w2<16;w2++) c += __popc(mw[w2] & ia[w2]);
        cnt[a] = (float)c;
    }
    #pragma unroll
    for(int a=0;a<NATOMS;a++){
        cnt[a] += __shfl_xor(cnt[a],1,64);
        cnt[a] += __shfl_xor(cnt[a],2,64);
    }
    float deg = (float)degi;
    deg += __shfl_xor(deg,1,64);
    deg += __shfl_xor(deg,2,64);

    // --- v = emb[own] + (sum_a cnt_a emb_a)/max(deg,1) -> LDS bf16 ----------
    {
        float inv = 1.0f / fmaxf(deg, 1.0f);
        int oid = sid[tile*64 + node];
        int d0 = p*32;
        float vv[32];
        #pragma unroll
        for(int d=0;d<32;d++) vv[d]=0.f;
        #pragma unroll
        for(int a=0;a<NATOMS;a++){
            float ca = cnt[a];
            const float* ea = &emb[a*128 + d0];
            #pragma unroll
            for(int d=0;d<32;d+=4){
                float4 e = *(const float4*)&ea[d];
                vv[d]+=ca*e.x; vv[d+1]+=ca*e.y; vv[d+2]+=ca*e.z; vv[d+3]+=ca*e.w;
            }
        }
        const float* eo = &emb[oid*128 + d0];
        unsigned short* dst = &v_bf[node*136 + d0];
        #pragma unroll
        for(int d=0;d<32;d+=4){
            float4 e = *(const float4*)&eo[d];
            ushort4 o;
            o.x = f2b(e.x + vv[d]*inv);
            o.y = f2b(e.y + vv[d+1]*inv);
            o.z = f2b(e.z + vv[d+2]*inv);
            o.w = f2b(e.w + vv[d+3]*inv);
            *(ushort4*)&dst[d] = o;
        }
    }
    __syncthreads();     // v complete; lmask/ind/sid/emb dead -> arena = sB

    // ---- hout = gelu(v @ W_msg + b), 2-term W split, A direct from v_bf ----
    f32x4 acc[2][4];
    #pragma unroll
    for(int i=0;i<2;i++)
        #pragma unroll
        for(int j=0;j<4;j++) acc[i][j] = (f32x4){0.f,0.f,0.f,0.f};
    for(int k0=0;k0<128;k0+=32){
        #pragma unroll
        for(int i=0;i<4;i++){                           // B: Wmsg_t [128][32]
            int id = tid + i*256; int plane = id>>9, cid = id&511;
            int r = cid>>2, c = cid&3;
            const short* src = (plane? wmtl : wmth) + (size_t)r*128 + k0 + c*8;
            short* dst = (plane? sBl : sBh) + r*40 + c*8;
            *(bf16x8*)dst = *(const bf16x8*)src;
        }
        __syncthreads();
        bf16x8 av[2];
        #pragma unroll
        for(int tm=0;tm<2;tm++)
            av[tm] = *(const bf16x8*)&v_bf[(m0w+tm*16+ln)*136 + k0 + quad*8];
        #pragma unroll
        for(int tn=0;tn<4;tn++){
            bf16x8 bh = *(const bf16x8*)&sBh[(n0w+tn*16+ln)*40 + quad*8];
            bf16x8 bl = *(const bf16x8*)&sBl[(n0w+tn*16+ln)*40 + quad*8];
            #pragma unroll
            for(int tm=0;tm<2;tm++){
                acc[tm][tn] = __builtin_amdgcn_mfma_f32_16x16x32_bf16(av[tm], bl, acc[tm][tn], 0,0,0);
                acc[tm][tn] = __builtin_amdgcn_mfma_f32_16x16x32_bf16(av[tm], bh, acc[tm][tn], 0,0,0);
            }
        }
        __syncthreads();
    }
    // epilogue: z fp32 + hout bf16 to LDS
    #pragma unroll
    for(int tn=0;tn<4;tn++){
        int col = n0w + tn*16 + ln;
        float bias = s_bm[col];
        #pragma unroll
        for(int tm=0;tm<2;tm++){
            int mb2 = m0w + tm*16 + quad*4;
            #pragma unroll
            for(int r=0;r<4;r++){
                float hv = gelu_f(acc[tm][tn][r] + bias);
                out_z[(size_t)(row0+mb2+r)*128 + col] = hv;
                houts[(mb2+r)*136 + col] = f2b(hv);
            }
        }
    }
    __syncthreads();

    // ---- coors: 4-lane k-split dot with w_coor -----------------------------
    {
        float d0=0.f, d1=0.f, d2=0.f;
        int kb = p*32;
        #pragma unroll
        for(int k=0;k<32;k+=4){
            ushort4 hv = *(const ushort4*)&houts[node*136 + kb + k];
            float h0=b2f(hv.x),h1=b2f(hv.y),h2=b2f(hv.z),h3=b2f(hv.w);
            const float* wc = &s_wc[(kb+k)*3];
            d0 += h0*wc[0]+h1*wc[3]+h2*wc[6]+h3*wc[9];
            d1 += h0*wc[1]+h1*wc[4]+h2*wc[7]+h3*wc[10];
            d2 += h0*wc[2]+h1*wc[5]+h2*wc[8]+h3*wc[11];
        }
        d0 += __shfl_xor(d0,1,64); d0 += __shfl_xor(d0,2,64);
        d1 += __shfl_xor(d1,1,64); d1 += __shfl_xor(d1,2,64);
        d2 += __shfl_xor(d2,1,64); d2 += __shfl_xor(d2,2,64);
        if(p==0){
            size_t o = (size_t)(row0+node)*3;
            out_co[o+0] = coords[o+0] + tanhf(d0);
            out_co[o+1] = coords[o+1] + tanhf(d1);
            out_co[o+2] = coords[o+2] + tanhf(d2);
        }
    }

    // ---- t1 = gelu(hout @ A1 + a1), 2-term split, N=128 (cols>=100 zero) ---
    f32x4 acc2[2][4];
    #pragma unroll
    for(int i=0;i<2;i++)
        #pragma unroll
        for(int j=0;j<4;j++) acc2[i][j] = (f32x4){0.f,0.f,0.f,0.f};
    for(int k0=0;k0<128;k0+=32){
        __syncthreads();                    // protect sB reuse across iters
        #pragma unroll
        for(int i=0;i<4;i++){
            int id = tid + i*256; int plane = id>>9, cid = id&511;
            int r = cid>>2, c = cid&3;
            const short* src = (plane? a1tl : a1th) + (size_t)r*128 + k0 + c*8;
            short* dst = (plane? sBl : sBh) + r*40 + c*8;
            *(bf16x8*)dst = *(const bf16x8*)src;
        }
        __syncthreads();
        bf16x8 ah[2];
        #pragma unroll
        for(int tm=0;tm<2;tm++)
            ah[tm] = *(const bf16x8*)&houts[(m0w+tm*16+ln)*136 + k0 + quad*8];
        #pragma unroll
        for(int tn=0;tn<4;tn++){
            bf16x8 bh = *(const bf16x8*)&sBh[(n0w+tn*16+ln)*40 + quad*8];
            bf16x8 bl = *(const bf16x8*)&sBl[(n0w+tn*16+ln)*40 + quad*8];
            #pragma unroll
            for(int tm=0;tm<2;tm++){
                acc2[tm][tn] = __builtin_amdgcn_mfma_f32_16x16x32_bf16(ah[tm], bl, acc2[tm][tn], 0,0,0);
                acc2[tm][tn] = __builtin_amdgcn_mfma_f32_16x16x32_bf16(ah[tm], bh, acc2[tm][tn], 0,0,0);
            }
        }
    }
    __syncthreads();                        // houts reads done -> reuse as t1s
    unsigned short* t1s = houts;            // [64][104]
    #pragma unroll
    for(int tn=0;tn<4;tn++){
        int col = n0w + tn*16 + ln;
        if(col < 104){
            float bias = s_a1[col];
            #pragma unroll
            for(int tm=0;tm<2;tm++){
                int mb2 = m0w + tm*16 + quad*4;
                #pragma unroll
                for(int r=0;r<4;r++)
                    t1s[(mb2+r)*104 + col] = f2b(gelu_f(acc2[tm][tn][r] + bias));
            }
        }
    }
    __syncthreads();

    // ---- t2 = gelu(t1@A2+a2); DyT; angles ----------------------------------
    {
        int g0 = (p<2) ? p*7 : 14+(p-2)*6;
        int gcount = (p<2) ? 7 : 6;
        float s[6] = {0.f,0.f,0.f,0.f,0.f,0.f};
        for(int gg=0; gg<gcount; gg++){
            int kb = (g0+gg)*4;
            ushort4 tv = *(const ushort4*)&t1s[node*104 + kb];
            float u0=b2f(tv.x), u1=b2f(tv.y), u2=b2f(tv.z), u3=b2f(tv.w);
            #pragma unroll
            for(int j=0;j<6;j++)
                s[j] += u0*s_A2[kb*6+j] + u1*s_A2[(kb+1)*6+j]
                      + u2*s_A2[(kb+2)*6+j] + u3*s_A2[(kb+3)*6+j];
        }
        #pragma unroll
        for(int j=0;j<6;j++){ s[j]+=__shfl_xor(s[j],1,64); s[j]+=__shfl_xor(s[j],2,64); }
        if(p<2){
            size_t o = (size_t)(row0+node)*6 + p*3;
            #pragma unroll
            for(int jj=0;jj<3;jj++){
                int j = p*3+jj;
                float t2v = gelu_f(s[j] + s_a2[j]);
                float uu = tanhf(s_dyt[0]*t2v)*s_dyt[1+j] + s_dyt[8+j];
                out_ang[o+jj] = tanhf(uu);
            }
        }
    }
}

// ---------------------------------------------------------------------------
extern "C" void kernel_launch(void* const* d_in, const int* in_sizes, int n_in,
                              void* d_out, int out_size, void* d_ws, size_t ws_size,
                              hipStream_t stream) {
    const float* x      = (const float*)d_in[0];
    const float* coords = (const float*)d_in[1];
    const int*   ei     = (const int*)d_in[2];
    const float* gamma  = (const float*)d_in[4];
    const float* beta   = (const float*)d_in[5];
    const float* W1     = (const float*)d_in[6];
    const float* b1     = (const float*)d_in[7];
    const float* W2     = (const float*)d_in[8];
    const float* b2     = (const float*)d_in[9];
    const float* W3     = (const float*)d_in[10];
    const float* b3     = (const float*)d_in[11];
    const float* embed  = (const float*)d_in[12];
    const float* W_msg  = (const float*)d_in[13];
    const float* b_msg  = (const float*)d_in[14];
    const float* w_coor = (const float*)d_in[15];
    const float* A1     = (const float*)d_in[16];
    const float* a1v    = (const float*)d_in[17];
    const float* A2     = (const float*)d_in[18];
    const float* a2v    = (const float*)d_in[19];
    const float* dalpha = (const float*)d_in[20];
    const float* dw     = (const float*)d_in[21];
    const float* db     = (const float*)d_in[22];

    // ws layout (~44 MB peak):
    //  0      : ids   (128 KB)
    //  128K   : stats (2 KB) + ecnt (2 KB)   <- one 4 KB memset
    //  256K   : weight planes (512 KB)
    //  1M     : earena u32[512*3072] (6 MB)
    //  10M    : h1h u16 (16.78 MB)
    //  27M    : h1l u16 (16.78 MB)
    char* ws = (char*)d_ws;
    int*      ids   = (int*)ws;
    float*    stats = (float*)(ws + 131072);
    unsigned* ecnt  = (unsigned*)(ws + 131072 + 2048);
    short*    w1th  = (short*)(ws + 262144);
    short*    w1tl  = w1th + 65536;
    short*    w2th  = w1tl + 65536;
    short*    w2tl  = w2th + 32768;
    short*    wmth  = w2tl + 32768;
    short*    wmtl  = wmth + 16384;
    short*    a1th  = wmtl + 16384;
    short*    a1tl  = a1th + 16384;
    unsigned* earena = (unsigned*)(ws + (1<<20));
    unsigned short* h1h = (unsigned short*)(ws + (size_t)10*1048576);
    unsigned short* h1l = (unsigned short*)(ws + (size_t)27*1048576);

    float* out_ang = (float*)d_out;
    float* out_z   = out_ang + (size_t)NT*OUTC;
    float* out_co  = out_z   + (size_t)NT*DIMd;

    hipMemsetAsync(stats, 0, 4096, stream);      // stats + ecnt
    prep0_k<<<320, 256, 0, stream>>>(x, stats, W1, W2, W_msg, A1,
        w1th, w1tl, w2th, w2tl, wmth, wmtl, a1th, a1tl);
    gemm1_scat_k<<<512, 256, 0, stream>>>(x, stats, gamma, beta, w1th, w1tl, b1,
        h1h, h1l, ei, ecnt, earena);
    gemm23_mfma<<<512, 256, 0, stream>>>(h1h, h1l, w2th, w2tl, b2, W3, b3, ids);
    msg3_k<<<512, 256, 0, stream>>>(ids, ecnt, earena, embed, wmth, wmtl, b_msg,
        w_coor, a1th, a1tl, a1v, A2, a2v, dalpha, dw, db, coords,
        out_ang, out_z, out_co);
}